// Round 4
// baseline (27.599 us; speedup 1.0000x reference)
//
#include <hip/hip_runtime.h>
#include <math.h>

#define THREADS    512
#define EPB        32      // elements per block
#define NI         9
#define NT         17
#define DEPTH      8

#define MAG_MAX    1e28f
#define MAG_MIN    1e-12f
#define LOG_LIM    100.0f
#define LOG_MAG_MIN (-27.631021115928547f)   // logf(1e-12)

typedef __attribute__((address_space(1))) const unsigned char gconst_byte;
typedef __attribute__((address_space(3))) unsigned char lds_byte;

__device__ __forceinline__ void gl_lds16(const float* g, float* l) {
    __builtin_amdgcn_global_load_lds((gconst_byte*)(const void*)g,
                                     (lds_byte*)(void*)l, 16, 0, 0);
}

__device__ __forceinline__ float tanh_fast(float x) {
    float e = __expf(2.0f * x);
    return 1.0f - 2.0f / (e + 1.0f);
}

__global__ __launch_bounds__(THREADS, 8)
void dag_exec_kernel(const float* __restrict__ dl,   // [NE,9,8,10]
                     const float* __restrict__ vsg,  // [NE,17]
                     const float* __restrict__ Og,   // [NE,8,17]
                     const float* __restrict__ Gg,   // [NE,8]
                     float* __restrict__ out)        // [NE]
{
    __shared__ float s_dl[2560];        // 10 KB digit chunk buffer (320 dw/wave)
    __shared__ float s_init[EPB * 9];   // per-(elem,node) initial magnitudes
    __shared__ float s_O[EPB * 136];    // linear — global_load_lds destination
    __shared__ float s_vs[EPB * NT];
    __shared__ float s_G[EPB * 9];

    const int tid  = threadIdx.x;
    const int lane = tid & 63;
    const int w    = tid >> 6;          // 8 waves
    const long e0  = (long)blockIdx.x * EPB;

    const float* Dg = dl + e0 * 720;
    const float* gw = Dg + w * 320;     // wave-local slice of each 2560-dw chunk
    float* lb = s_dl + w * 320;

    // ---- chunk 0 -> regs (coalesced: float4 + float) ----
    float4 r0 = *(const float4*)(gw + lane * 4);
    float  r1 = gw[256 + lane];

    // ---- O -> LDS direct, coalesced width-16 global_load_lds ----
    {
        const float* Ob = Og + e0 * 136;
        gl_lds16(Ob + w * 256 + lane * 4,       s_O + w * 256);
        gl_lds16(Ob + (w + 8) * 256 + lane * 4, s_O + (w + 8) * 256);
        if (w == 0)
            gl_lds16(Ob + 16 * 256 + lane * 4,  s_O + 16 * 256);
    }
    // ---- V_sign, G ----
    {
        const float* Vb = vsg + e0 * NT;
        s_vs[tid] = Vb[tid];
        if (tid < 32) s_vs[tid + 512] = Vb[tid + 512];
        if (tid < 256) s_G[(tid >> 3) * 9 + (tid & 7)] = Gg[e0 * 8 + tid];
    }

    // ---- store chunk 0 (wave-local region) ----
    *(float4*)(lb + lane * 4) = r0;
    lb[256 + lane] = r1;

    const int h    = tid & 1;                 // half-slot: digits [h*5, h*5+5)
    const int dpos = (tid >> 1) & 7;          // place-value position (const/thread)
    const float powv = (dpos == 0) ? 1000.0f : (dpos == 1) ? 100.0f : (dpos == 2) ? 10.0f :
                       (dpos == 3) ? 1.0f    : (dpos == 4) ? 0.1f   : (dpos == 5) ? 0.01f :
                       (dpos == 6) ? 0.001f  : 0.0001f;
    const float base_digit = (float)(h * 5);

    // ---- phase 1: 9 chunks, wave-local single-buffer pipeline, no barriers ----
    #pragma unroll
    for (int c = 0; c < 9; ++c) {
        float4 n0; float n1;
        if (c < 8) {                          // prefetch next chunk into regs
            const float* gn = Dg + (c + 1) * 2560 + w * 320;
            n0 = *(const float4*)(gn + lane * 4);
            n1 = gn[256 + lane];
        }

        const float* p = s_dl + tid * 5;      // this thread's 5 logits
        float x0 = p[0], x1 = p[1], x2 = p[2], x3 = p[3], x4 = p[4];
        float m = fmaxf(fmaxf(fmaxf(x0, x1), fmaxf(x2, x3)), x4);
        m = fmaxf(m, __shfl_xor(m, 1));       // pair max -> full-slot max
        float t0 = __expf((x0 - m) * 100.0f);
        float t1 = __expf((x1 - m) * 100.0f);
        float t2 = __expf((x2 - m) * 100.0f);
        float t3 = __expf((x3 - m) * 100.0f);
        float t4 = __expf((x4 - m) * 100.0f);
        float den = t0 + t1 + t2 + t3 + t4;
        float num = t1 + t2 * 2.0f + t3 * 3.0f + t4 * 4.0f + base_digit * den;
        den += __shfl_xor(den, 1);
        num += __shfl_xor(num, 1);
        float contrib = (num / den) * powv;   // expected digit * place value
        // 8 digit positions of one (elem,node) live in 16 consecutive lanes
        contrib += __shfl_xor(contrib, 2);
        contrib += __shfl_xor(contrib, 4);
        contrib += __shfl_xor(contrib, 8);
        if ((tid & 15) == 0) {
            int en = (c * 512 + tid) >> 4;    // = el*9 + node
            s_init[en] = contrib;
        }

        if (c < 8) {                          // overwrite own region (in-order DS)
            *(float4*)(lb + lane * 4) = n0;
            lb[256 + lane] = n1;
        }
    }

    __syncthreads();   // drains vmcnt (O gl_lds) + lgkmcnt; all LDS visible

    // ---- phase 2: DAG, lane PAIR per element (nodes split by parity) ----
    if (tid < 64) {
        const int el = tid >> 1;              // h = tid & 1; lane owns nodes 2k+h
        float sgnL[8], logmL[8], svL[8];      // nodes 0..15 (node 16 never re-read)
        #pragma unroll
        for (int k = 0; k < 8; ++k) {
            int n = 2 * k + h;
            if (n < NI) {                     // runtime predicate, static indices
                float v  = fminf(fmaxf(s_init[el * 9 + n], MAG_MIN), MAG_MAX);
                float sg = s_vs[el * NT + n];
                sgnL[k] = sg; logmL[k] = logf(v); svL[k] = sg * v;
            } else {
                sgnL[k] = 0.0f; logmL[k] = LOG_MAG_MIN; svL[k] = 0.0f;
            }
        }

        float resS = 0.0f, resM = 0.0f;
        #pragma unroll
        for (int step = 0; step < DEPTH; ++step) {
            const int valid = NI + step;
            float g  = s_G[el * 9 + step];
            float og = 1.0f - g;
            float Rp = 0.0f, Pp = 1.0f;
            #pragma unroll
            for (int k = 0; k < 8; ++k) {
                int n = 2 * k + h;
                float o = s_O[el * 136 + step * 17 + n];
                o = (n < valid) ? o : 0.0f;   // causal mask
                float mixed = logmL[k] * og + svL[k] * g;
                Rp += o * mixed;
                Pp *= sgnL[k] * fabsf(o) * 2.0f + 1.0f;
            }
            float R    = Rp + __shfl_xor(Rp, 1);
            float prod = Pp * __shfl_xor(Pp, 1);

            float linear_sign = tanh_fast(R * 10000.0f);
            float log_sign    = tanh_fast(prod * 10000.0f);
            float s_new = g * linear_sign + og * log_sign;
            float linear_mag  = fminf(fabsf(R), MAG_MAX);
            float Rc = fminf(fmaxf(R, -LOG_LIM), LOG_LIM);
            float log_mag_res = expf(Rc);
            float m_new = g * linear_mag + og * log_mag_res;
            m_new = fminf(fmaxf(m_new, MAG_MIN), MAG_MAX);
            s_new = fminf(fmaxf(s_new, -1.0f), 1.0f);

            if (step < 7) {                   // store node idx=9+step into its owner
                const int idx = NI + step;
                const int kk  = idx >> 1;     // compile-time
                bool own = (h == (idx & 1));
                float lm = logf(m_new);
                sgnL[kk]  = own ? s_new         : sgnL[kk];
                logmL[kk] = own ? lm            : logmL[kk];
                svL[kk]   = own ? s_new * m_new : svL[kk];
            } else {
                resS = s_new; resM = m_new;   // node 16
            }
        }
        if (h == 0) out[e0 + el] = resS * resM;
    }
}

extern "C" void kernel_launch(void* const* d_in, const int* in_sizes, int n_in,
                              void* d_out, int out_size, void* d_ws, size_t ws_size,
                              hipStream_t stream) {
    const float* dl  = (const float*)d_in[0];   // digit_logits [B,T,9,8,10]
    const float* vsg = (const float*)d_in[1];   // V_sign       [B,T,17]
    const float* Og  = (const float*)d_in[2];   // O            [B,T,8,17]
    const float* Gg  = (const float*)d_in[3];   // G            [B,T,8]
    float* out = (float*)d_out;

    const int ne = out_size;                    // 32768
    const int blocks = ne / EPB;                // 1024
    dag_exec_kernel<<<blocks, THREADS, 0, stream>>>(dl, vsg, Og, Gg, out);
}

// Round 5
// 27.134 us; speedup vs baseline: 1.0171x; 1.0171x over previous
//
#include <hip/hip_runtime.h>
#include <math.h>

#define THREADS    256
#define EPB        32      // elements per block
#define NI         9
#define NT         17
#define DEPTH      8

#define MAG_MAX    1e28f
#define MAG_MIN    1e-12f
#define LOG_LIM    100.0f

typedef __attribute__((address_space(1))) const unsigned char gconst_byte;
typedef __attribute__((address_space(3))) unsigned char lds_byte;

__device__ __forceinline__ void gl_lds16(const float* g, float* l) {
    __builtin_amdgcn_global_load_lds((gconst_byte*)(const void*)g,
                                     (lds_byte*)(void*)l, 16, 0, 0);
}

__device__ __forceinline__ float tanh_fast(float x) {
    float e = __expf(2.0f * x);
    return 1.0f - 2.0f / (e + 1.0f);
}

__global__ __launch_bounds__(THREADS, 4)
void dag_exec_kernel(const float* __restrict__ dl,   // [NE,9,8,10]
                     const float* __restrict__ vsg,  // [NE,17]
                     const float* __restrict__ Og,   // [NE,8,17]
                     const float* __restrict__ Gg,   // [NE,8]
                     float* __restrict__ out)        // [NE]
{
    __shared__ float s_dl[2560];        // 10 KB digit chunk buffer (640 dw/wave)
    __shared__ float s_init[EPB * 9];   // per-(elem,node) initial magnitudes
    __shared__ float s_O[EPB * 136];    // linear — global_load_lds destination
    __shared__ float s_vs[EPB * NT];
    __shared__ float s_G[EPB * 9];

    const int tid  = threadIdx.x;
    const int lane = tid & 63;
    const int w    = tid >> 6;          // 4 waves
    const long e0  = (long)blockIdx.x * EPB;

    const float* Dg = dl + e0 * 720;
    const float* gw = Dg + w * 640;     // this wave's slice; chunk c at +c*2560
    float* lb = s_dl + w * 640;

    // ---- depth-2 register pipeline: issue chunks 0 and 1 now ----
    float4 A0[3], A1[3];
    float2 A2[3];
    A0[0] = *(const float4*)(gw + lane * 4);
    A1[0] = *(const float4*)(gw + 256 + lane * 4);
    A2[0] = *(const float2*)(gw + 512 + lane * 2);
    A0[1] = *(const float4*)(gw + 2560 + lane * 4);
    A1[1] = *(const float4*)(gw + 2560 + 256 + lane * 4);
    A2[1] = *(const float2*)(gw + 2560 + 512 + lane * 2);

    // ---- O -> LDS direct, coalesced width-16 global_load_lds (17 segs) ----
    {
        const float* Ob = Og + e0 * 136;
        #pragma unroll
        for (int k = 0; k < 4; ++k) {
            int i = w + k * 4;                        // wave-uniform LDS base
            gl_lds16(Ob + i * 256 + lane * 4, s_O + i * 256);
        }
        if (w == 0)
            gl_lds16(Ob + 16 * 256 + lane * 4, s_O + 16 * 256);
    }
    // ---- V_sign, G (small, coalesced) ----
    {
        const float* Vb = vsg + e0 * NT;
        s_vs[tid]       = Vb[tid];
        s_vs[tid + 256] = Vb[tid + 256];
        if (tid < 32) s_vs[tid + 512] = Vb[tid + 512];
        s_G[(tid >> 3) * 9 + (tid & 7)] = Gg[e0 * 8 + tid];
    }

    const int dpos = tid & 7;
    const float powv = (dpos == 0) ? 1000.0f : (dpos == 1) ? 100.0f : (dpos == 2) ? 10.0f :
                       (dpos == 3) ? 1.0f    : (dpos == 4) ? 0.1f   : (dpos == 5) ? 0.01f :
                       (dpos == 6) ? 0.001f  : 0.0001f;

    // ---- phase 1: 9 chunks, rolling depth-2 pipeline, wave-local, no barriers ----
    #pragma unroll
    for (int c = 0; c < 9; ++c) {
        const int cur = c % 3;                        // compile-time under unroll
        const int pre = (c + 2) % 3;
        if (c + 2 < 9) {                              // issue chunk c+2 (2-iter slack)
            const float* gn = gw + (c + 2) * 2560;
            A0[pre] = *(const float4*)(gn + lane * 4);
            A1[pre] = *(const float4*)(gn + 256 + lane * 4);
            A2[pre] = *(const float2*)(gn + 512 + lane * 2);
        }

        // write chunk c (its loads were issued 2 iterations ago -> latency hidden)
        *(float4*)(lb + lane * 4)       = A0[cur];
        *(float4*)(lb + 256 + lane * 4) = A1[cur];
        *(float2*)(lb + 512 + lane * 2) = A2[cur];

        const float* p = lb + lane * 10;              // own slot, own wave region
        float2 a0 = *(const float2*)(p + 0);
        float2 a1 = *(const float2*)(p + 2);
        float2 a2 = *(const float2*)(p + 4);
        float2 a3 = *(const float2*)(p + 6);
        float2 a4 = *(const float2*)(p + 8);
        float x0 = a0.x, x1 = a0.y, x2 = a1.x, x3 = a1.y, x4 = a2.x;
        float x5 = a2.y, x6 = a3.x, x7 = a3.y, x8 = a4.x, x9 = a4.y;
        float m = fmaxf(x0, x1);
        m = fmaxf(m, x2); m = fmaxf(m, x3); m = fmaxf(m, x4);
        m = fmaxf(m, x5); m = fmaxf(m, x6); m = fmaxf(m, x7);
        m = fmaxf(m, x8); m = fmaxf(m, x9);
        float e0v = __expf((x0 - m) * 100.0f);
        float e1v = __expf((x1 - m) * 100.0f);
        float e2v = __expf((x2 - m) * 100.0f);
        float e3v = __expf((x3 - m) * 100.0f);
        float e4v = __expf((x4 - m) * 100.0f);
        float e5v = __expf((x5 - m) * 100.0f);
        float e6v = __expf((x6 - m) * 100.0f);
        float e7v = __expf((x7 - m) * 100.0f);
        float e8v = __expf((x8 - m) * 100.0f);
        float e9v = __expf((x9 - m) * 100.0f);
        float den = e0v + e1v + e2v + e3v + e4v + e5v + e6v + e7v + e8v + e9v;
        float num = e1v + e2v * 2.0f + e3v * 3.0f + e4v * 4.0f +
                    e5v * 5.0f + e6v * 6.0f + e7v * 7.0f + e8v * 8.0f + e9v * 9.0f;
        float contrib = (num / den) * powv;

        // 8 consecutive lanes hold the 8 digit positions of one (elem,node)
        contrib += __shfl_xor(contrib, 1);
        contrib += __shfl_xor(contrib, 2);
        contrib += __shfl_xor(contrib, 4);
        if (dpos == 0) {
            int en = (c * 256 + tid) >> 3;            // = el*9 + node
            s_init[en] = contrib;
        }
    }

    __syncthreads();    // drains vmcnt (O gl_lds) + lgkmcnt; all LDS visible

    // ---- phase 2: DAG, one thread per element ----
    if (tid < EPB) {
        float vmag[NT], sgn[NT], logm[NT], sv[NT];
        #pragma unroll
        for (int n = 0; n < NI; ++n) {
            float v = s_init[tid * 9 + n];
            v = fminf(fmaxf(v, MAG_MIN), MAG_MAX);
            vmag[n] = v;
            sgn[n]  = s_vs[tid * NT + n];
            logm[n] = logf(v);
            sv[n]   = sgn[n] * v;
        }
        #pragma unroll
        for (int n = NI; n < NT; ++n) {
            vmag[n] = 0.0f; sgn[n] = 0.0f;
            logm[n] = logf(MAG_MIN);
            sv[n]   = 0.0f;
        }

        #pragma unroll
        for (int step = 0; step < DEPTH; ++step) {
            const int valid = NI + step;
            float g  = s_G[tid * 9 + step];
            float og = 1.0f - g;
            float R = 0.0f;
            float prod = 1.0f;
            #pragma unroll
            for (int n = 0; n < NT; ++n) {
                if (n < valid) {
                    float o = s_O[tid * 136 + step * 17 + n];
                    float mixed = logm[n] * og + sv[n] * g;
                    R += o * mixed;
                    float wgt = sgn[n] * fabsf(o) * 2.0f + 1.0f;
                    prod *= wgt;
                }
            }
            float linear_sign = tanh_fast(R * 10000.0f);
            float log_sign    = tanh_fast(prod * 10000.0f);
            float s_new = g * linear_sign + og * log_sign;
            float linear_mag  = fminf(fabsf(R), MAG_MAX);
            float Rc = fminf(fmaxf(R, -LOG_LIM), LOG_LIM);
            float log_mag_res = expf(Rc);
            float m_new = g * linear_mag + og * log_mag_res;
            m_new = fminf(fmaxf(m_new, MAG_MIN), MAG_MAX);
            s_new = fminf(fmaxf(s_new, -1.0f), 1.0f);
            vmag[valid] = m_new;
            sgn[valid]  = s_new;
            logm[valid] = logf(m_new);
            sv[valid]   = s_new * m_new;
        }
        out[e0 + tid] = sgn[NT - 1] * vmag[NT - 1];
    }
}

extern "C" void kernel_launch(void* const* d_in, const int* in_sizes, int n_in,
                              void* d_out, int out_size, void* d_ws, size_t ws_size,
                              hipStream_t stream) {
    const float* dl  = (const float*)d_in[0];   // digit_logits [B,T,9,8,10]
    const float* vsg = (const float*)d_in[1];   // V_sign       [B,T,17]
    const float* Og  = (const float*)d_in[2];   // O            [B,T,8,17]
    const float* Gg  = (const float*)d_in[3];   // G            [B,T,8]
    float* out = (float*)d_out;

    const int ne = out_size;                    // 32768
    const int blocks = ne / EPB;                // 1024
    dag_exec_kernel<<<blocks, THREADS, 0, stream>>>(dl, vsg, Og, Gg, out);
}